// Round 3
// baseline (1968.049 us; speedup 1.0000x reference)
//
#include <hip/hip_runtime.h>

// Segmented GroupNorm: N rows x C=128 channels, G=32 groups, Cg=4.
// group g == float4 element index (i & 31); channels 4g..4g+3.
//
// Strategy (this round): counting-sort rows by segment to eliminate the
// per-element DS-atomic bottleneck (measured ~200cy/wave-op, pass1 was
// DS-atomic-throughput-bound at 4.8% VALUBusy / 11% HBM):
//   H: LDS histogram of seg            (1 atomic per ROW, not per row*group*2)
//   P: prefix sum -> bounds/cursor     (1 block, trivial)
//   S: scatter sorted row ids          (1M u32 atomics on 100 L2-hot counters)
//   C: reduce over sorted rows         (register accumulation, flush at seg
//                                       boundaries only: ~2 global atomics/thread)
//   finalize + pass2 unchanged.
// Legacy atomic pass1 kept as fallback if ws_size < ~4.2MB (rowidx).

#define C_CHANNELS 128
#define GROUPS 32
#define SEG_CAP 256        // bin capacity
#define LDS_SEG_CAP 104    // legacy path LDS bin capacity
#define EPS 1e-5f

typedef float f32x4 __attribute__((ext_vector_type(4)));

__device__ __forceinline__ void nt_store4(float4* p, const float4& v) {
    f32x4 t; t.x = v.x; t.y = v.y; t.z = v.z; t.w = v.w;
    __builtin_nontemporal_store(t, (f32x4*)p);
}

// ---------------------------------------------------------------- histogram
__global__ __launch_bounds__(256) void gn_hist(
    const int* __restrict__ seg, unsigned* __restrict__ histU, int N)
{
    __shared__ unsigned h[SEG_CAP];
    for (int t = threadIdx.x; t < SEG_CAP; t += blockDim.x) h[t] = 0u;
    __syncthreads();
    int stride = gridDim.x * blockDim.x;
    for (int r = blockIdx.x * blockDim.x + threadIdx.x; r < N; r += stride) {
        int s = seg[r];
        if ((unsigned)s < SEG_CAP) atomicAdd(&h[s], 1u);
    }
    __syncthreads();
    for (int t = threadIdx.x; t < SEG_CAP; t += blockDim.x) {
        unsigned c = h[t];
        if (c) atomicAdd(&histU[t], c);
    }
}

// ------------------------------------------------- prefix sum, cursor, counts
__global__ __launch_bounds__(64) void gn_prefix(
    const unsigned* __restrict__ histU, unsigned* __restrict__ boundsU,
    unsigned* __restrict__ cursorU, float* __restrict__ gcntf,
    const int* __restrict__ nInstPtr)
{
    if (threadIdx.x == 0 && blockIdx.x == 0) {
        int S = *nInstPtr;
        if (S > SEG_CAP) S = SEG_CAP;
        unsigned run = 0;
        for (int s = 0; s < S; ++s) {
            unsigned c = histU[s];
            boundsU[s] = run;
            cursorU[s] = run;
            gcntf[s]   = (float)c;
            run += c;
        }
        boundsU[S] = run;
    }
}

// ---------------------------------------------------------------- scatter
__global__ __launch_bounds__(256) void gn_scatter(
    const int* __restrict__ seg, unsigned* __restrict__ cursorU,
    unsigned* __restrict__ rowidx, int N)
{
    int stride = gridDim.x * blockDim.x;
    for (int r = blockIdx.x * blockDim.x + threadIdx.x; r < N; r += stride) {
        int s = seg[r];
        if ((unsigned)s < SEG_CAP) {
            unsigned pos = atomicAdd(&cursorU[s], 1u);
            rowidx[pos] = (unsigned)r;
        }
    }
}

// ------------------------------------------------------- reduce (sorted rows)
// Each block owns a contiguous chunk of sorted positions. Half-wave h
// (8 per block) visits positions start+h, start+h+8, ...; lane g accumulates
// (sum, sumsq) for its group in registers; flush at segment boundaries.
__global__ __launch_bounds__(256) void gn_reduce(
    const float4* __restrict__ x, const unsigned* __restrict__ rowidx,
    const unsigned* __restrict__ boundsU,
    float* __restrict__ gsum, float* __restrict__ gsq,
    const int* __restrict__ nInstPtr, int N)
{
    __shared__ int sb[SEG_CAP + 1];
    int S = *nInstPtr;
    if (S > SEG_CAP) S = SEG_CAP;
    for (int t = threadIdx.x; t <= S; t += blockDim.x) sb[t] = (int)boundsU[t];
    __syncthreads();

    const int h = threadIdx.x >> 5;     // half-wave id 0..7
    const int g = threadIdx.x & 31;     // group id
    int chunk = (N + gridDim.x - 1) / gridDim.x;
    int start = blockIdx.x * chunk;
    int end   = min(N, start + chunk);
    int p = start + h;
    if (p >= end) return;

    // binary search: largest k with sb[k] <= p
    int lo = 0, hi = S - 1;
    while (lo < hi) {
        int mid = (lo + hi) >> 1;
        if (sb[mid + 1] <= p) lo = mid + 1; else hi = mid;
    }
    int k = lo;

    float asum = 0.f, asq = 0.f;
    for (; p < end; p += 8) {
        while (p >= sb[k + 1]) {
            if (asum != 0.f || asq != 0.f) {
                unsafeAtomicAdd(&gsum[k * GROUPS + g], asum);
                unsafeAtomicAdd(&gsq [k * GROUPS + g], asq);
                asum = 0.f; asq = 0.f;
            }
            ++k;
        }
        int r = (int)rowidx[p];
        float4 v = x[(long long)r * GROUPS + g];
        asum += (v.x + v.y) + (v.z + v.w);
        asq  += v.x*v.x + v.y*v.y + v.z*v.z + v.w*v.w;
    }
    if (asum != 0.f || asq != 0.f) {
        unsafeAtomicAdd(&gsum[k * GROUPS + g], asum);
        unsafeAtomicAdd(&gsq [k * GROUPS + g], asq);
    }
}

// -------------------------------------------------------------- legacy pass1
__device__ __forceinline__ void lds_fadd(float* p, float v) {
    asm volatile("ds_add_f32 %0, %1"
                 :: "v"((unsigned)(unsigned long long)p), "v"(v));
}

__global__ __launch_bounds__(256) void gn_pass1(
    const float4* __restrict__ x, const int* __restrict__ seg,
    float* __restrict__ gsum, float* __restrict__ gsq, float* __restrict__ gcnt,
    const int* __restrict__ nInstPtr, int N)
{
    __shared__ float lsum[LDS_SEG_CAP * GROUPS];
    __shared__ float lsq [LDS_SEG_CAP * GROUPS];
    __shared__ float lcnt[LDS_SEG_CAP];

    for (int t = threadIdx.x; t < LDS_SEG_CAP * GROUPS; t += blockDim.x) {
        lsum[t] = 0.f; lsq[t] = 0.f;
    }
    for (int t = threadIdx.x; t < LDS_SEG_CAP; t += blockDim.x) lcnt[t] = 0.f;
    __syncthreads();

    const int g = threadIdx.x & 31;
    const long long total  = (long long)N * GROUPS;
    const long long stride = (long long)gridDim.x * blockDim.x;
    long long i = (long long)blockIdx.x * blockDim.x + threadIdx.x;
    for (; i < total; i += stride) {
        int row = (int)(i >> 5);
        float4 v = x[i];
        int s = seg[row];
        float a = (v.x + v.y) + (v.z + v.w);
        float q = v.x*v.x + v.y*v.y + v.z*v.z + v.w*v.w;
        if (s < LDS_SEG_CAP) {
            lds_fadd(&lsum[s * GROUPS + g], a);
            lds_fadd(&lsq [s * GROUPS + g], q);
            if (g == 0) lds_fadd(&lcnt[s], 1.0f);
        } else {
            unsafeAtomicAdd(&gsum[s * GROUPS + g], a);
            unsafeAtomicAdd(&gsq [s * GROUPS + g], q);
            if (g == 0) unsafeAtomicAdd(&gcnt[s], 1.0f);
        }
    }
    asm volatile("s_waitcnt lgkmcnt(0)" ::: "memory");
    __syncthreads();

    int S = *nInstPtr;
    int lim = min(S, LDS_SEG_CAP);
    int nb = lim * GROUPS;
    int rot = (int)((blockIdx.x * 64u) % (unsigned)nb);
    for (int t = threadIdx.x; t < nb; t += blockDim.x) {
        int j = t + rot; if (j >= nb) j -= nb;
        float a = lsum[j], b = lsq[j];
        if (a != 0.f || b != 0.f) {
            unsafeAtomicAdd(&gsum[j], a);
            unsafeAtomicAdd(&gsq [j], b);
        }
    }
    for (int t = threadIdx.x; t < lim; t += blockDim.x) {
        float c = lcnt[t];
        if (c != 0.f) unsafeAtomicAdd(&gcnt[t], c);
    }
}

// ---------------------------------------------------------------- finalize
__global__ __launch_bounds__(256) void gn_finalize(
    const float* __restrict__ gsum, const float* __restrict__ gsq,
    const float* __restrict__ gcnt, float2* __restrict__ stats,
    const int* __restrict__ nInstPtr)
{
    int S = *nInstPtr;
    int i = blockIdx.x * blockDim.x + threadIdx.x;
    if (i < S * GROUPS) {
        int s = i >> 5;
        float cnt = gcnt[s];
        float denom = fmaxf(cnt * 4.0f, 1.0f);
        float mean = gsum[i] / denom;
        float var  = gsq[i] / denom - mean * mean;
        float inv  = rsqrtf(var + EPS);
        stats[i] = make_float2(mean, inv);
    }
}

// ---------------------------------------------------------------- pass2
__global__ __launch_bounds__(256) void gn_pass2(
    const float4* __restrict__ x, const int* __restrict__ seg,
    const float2* __restrict__ stats,
    const float4* __restrict__ gamma4, const float4* __restrict__ beta4,
    float4* __restrict__ out, const int* __restrict__ nInstPtr, int N)
{
    __shared__ float lmean[LDS_SEG_CAP * GROUPS];
    __shared__ float linv [LDS_SEG_CAP * GROUPS];
    int S = *nInstPtr;
    int lim = min(S, LDS_SEG_CAP) * GROUPS;
    for (int t = threadIdx.x; t < lim; t += blockDim.x) {
        float2 mi = stats[t];
        lmean[t] = mi.x; linv[t] = mi.y;
    }
    __syncthreads();

    const int g = threadIdx.x & 31;
    const float4 gm = gamma4[g];
    const float4 bt = beta4[g];
    const long long total  = (long long)N * GROUPS;
    const long long stride = (long long)gridDim.x * blockDim.x;
    const int rowStride = (int)(stride >> 5);
    long long i = (long long)blockIdx.x * blockDim.x + threadIdx.x;

    for (; i + stride < total; i += 2 * stride) {
        int row0 = (int)(i >> 5);
        float4 v0 = x[i];
        float4 v1 = x[i + stride];
        int s0 = seg[row0];
        int s1 = seg[row0 + rowStride];

        float m0, iv0, m1, iv1;
        if (s0 < LDS_SEG_CAP) { m0 = lmean[s0 * GROUPS + g]; iv0 = linv[s0 * GROUPS + g]; }
        else { float2 t = stats[s0 * GROUPS + g]; m0 = t.x; iv0 = t.y; }
        if (s1 < LDS_SEG_CAP) { m1 = lmean[s1 * GROUPS + g]; iv1 = linv[s1 * GROUPS + g]; }
        else { float2 t = stats[s1 * GROUPS + g]; m1 = t.x; iv1 = t.y; }

        float4 o0, o1;
        o0.x = (v0.x - m0) * iv0 * gm.x + bt.x;
        o0.y = (v0.y - m0) * iv0 * gm.y + bt.y;
        o0.z = (v0.z - m0) * iv0 * gm.z + bt.z;
        o0.w = (v0.w - m0) * iv0 * gm.w + bt.w;
        o1.x = (v1.x - m1) * iv1 * gm.x + bt.x;
        o1.y = (v1.y - m1) * iv1 * gm.y + bt.y;
        o1.z = (v1.z - m1) * iv1 * gm.z + bt.z;
        o1.w = (v1.w - m1) * iv1 * gm.w + bt.w;

        nt_store4(&out[i], o0);
        nt_store4(&out[i + stride], o1);
    }
    for (; i < total; i += stride) {
        int row = (int)(i >> 5);
        float4 v = x[i];
        int s = seg[row];
        float m, iv;
        if (s < LDS_SEG_CAP) { m = lmean[s * GROUPS + g]; iv = linv[s * GROUPS + g]; }
        else { float2 t = stats[s * GROUPS + g]; m = t.x; iv = t.y; }
        float4 o;
        o.x = (v.x - m) * iv * gm.x + bt.x;
        o.y = (v.y - m) * iv * gm.y + bt.y;
        o.z = (v.z - m) * iv * gm.z + bt.z;
        o.w = (v.w - m) * iv * gm.w + bt.w;
        nt_store4(&out[i], o);
    }
}

extern "C" void kernel_launch(void* const* d_in, const int* in_sizes, int n_in,
                              void* d_out, int out_size, void* d_ws, size_t ws_size,
                              hipStream_t stream) {
    const float* feat  = (const float*)d_in[0];
    const int*   seg   = (const int*)d_in[1];
    const float* gamma = (const float*)d_in[2];
    const float* beta  = (const float*)d_in[3];
    const int*   nInst = (const int*)d_in[4];
    const int N = in_sizes[0] / C_CHANNELS;

    // ws layout (float-offset units):
    //   gsum    @0      [8192]f
    //   gsq     @8192   [8192]f
    //   histU   @16384  [256]u32      (zeroed with gsum/gsq: one memset)
    //   gcntf   @16640  [256]f
    //   cursorU @16896  [256]u32
    //   boundsU @17152  [260]u32
    //   stats   @17412  [8192]float2  (byte off 69648, 8B aligned)
    //   rowidx  @33796  [N]u32
    float*    base    = (float*)d_ws;
    float*    gsum    = base;
    float*    gsq     = base + 8192;
    unsigned* histU   = (unsigned*)(base + 16384);
    float*    gcntf   = base + 16640;
    unsigned* cursorU = (unsigned*)(base + 16896);
    unsigned* boundsU = (unsigned*)(base + 17152);
    float2*   stats   = (float2*)(base + 17412);
    unsigned* rowidx  = (unsigned*)(base + 33796);

    size_t need = (size_t)33796 * 4 + (size_t)N * 4;
    bool use_sorted = (ws_size >= need);

    if (use_sorted) {
        // zero gsum|gsq|histU in one contiguous memset
        (void)hipMemsetAsync(d_ws, 0, (size_t)(16384 + 256) * 4, stream);

        gn_hist<<<512, 256, 0, stream>>>(seg, histU, N);
        gn_prefix<<<1, 64, 0, stream>>>(histU, boundsU, cursorU, gcntf, nInst);
        gn_scatter<<<512, 256, 0, stream>>>(seg, cursorU, rowidx, N);
        gn_reduce<<<2048, 256, 0, stream>>>(
            (const float4*)feat, rowidx, boundsU, gsum, gsq, nInst, N);
        gn_finalize<<<(SEG_CAP * GROUPS + 255) / 256, 256, 0, stream>>>(
            gsum, gsq, gcntf, stats, nInst);
    } else {
        // legacy fallback: gcntf doubles as the atomic count buffer
        (void)hipMemsetAsync(d_ws, 0, (size_t)(16384 + 512) * 4, stream);
        gn_pass1<<<1536, 256, 0, stream>>>(
            (const float4*)feat, seg, gsum, gsq, gcntf, nInst, N);
        gn_finalize<<<(SEG_CAP * GROUPS + 255) / 256, 256, 0, stream>>>(
            gsum, gsq, gcntf, stats, nInst);
    }

    gn_pass2<<<1536, 256, 0, stream>>>(
        (const float4*)feat, seg, stats,
        (const float4*)gamma, (const float4*)beta,
        (float4*)d_out, nInst, N);
}

// Round 4
// 1013.854 us; speedup vs baseline: 1.9412x; 1.9412x over previous
//
#include <hip/hip_runtime.h>

// Segmented GroupNorm: N rows x C=128 channels, G=32 groups, Cg=4.
// group g == float4 element index (i & 31); channels 4g..4g+3.
//
// Pipeline (deterministic counting sort, zero contended global atomics):
//   A gn_histlocal : per-block histogram of seg -> blockhist[s][b]
//   B gn_scanseg   : per-seg exclusive scan over blocks (256 tiny scans)
//   C gn_bounds    : scan of seg totals -> bounds, counts
//   D gn_scatter_det: block base = bounds[s]+blockhist[s][b]; LDS rank atomics
//   E gn_reduce    : register-accumulating segmented reduce over sorted rows
//                    (~2 global atomics per thread, at segment boundaries only)
//   F gn_finalize  : mean/inv -> float2 stats table
//   G gn_pass2_sorted: gather-normalize-scatter in sorted order (512B bursts,
//                    wave-uniform seg/stats, nontemporal stores)
// Legacy DS-atomic pass1 + linear pass2 kept as fallback if ws too small.

#define C_CHANNELS 128
#define GROUPS 32
#define SEG_CAP 256
#define NBLK 256           // blocks for histlocal/scanseg/scatter (fixed)
#define LDS_SEG_CAP 104    // legacy path LDS bin capacity
#define EPS 1e-5f

typedef float f32x4 __attribute__((ext_vector_type(4)));

__device__ __forceinline__ void nt_store4(float4* p, const float4& v) {
    f32x4 t; t.x = v.x; t.y = v.y; t.z = v.z; t.w = v.w;
    __builtin_nontemporal_store(t, (f32x4*)p);
}

// ---------------------------------------------------------- A: local histogram
__global__ __launch_bounds__(256) void gn_histlocal(
    const int* __restrict__ seg, unsigned* __restrict__ blockhist, int N)
{
    __shared__ unsigned h[SEG_CAP];
    for (int t = threadIdx.x; t < SEG_CAP; t += 256) h[t] = 0u;
    __syncthreads();
    int chunk = (N + NBLK - 1) / NBLK;
    int start = blockIdx.x * chunk;
    int end   = min(N, start + chunk);
    for (int r = start + threadIdx.x; r < end; r += 256) {
        int s = seg[r];
        if ((unsigned)s < SEG_CAP) atomicAdd(&h[s], 1u);
    }
    __syncthreads();
    for (int t = threadIdx.x; t < SEG_CAP; t += 256)
        blockhist[t * NBLK + blockIdx.x] = h[t];
}

// ------------------------------------------- B: per-seg scan over blocks
__global__ __launch_bounds__(256) void gn_scanseg(
    unsigned* __restrict__ blockhist, unsigned* __restrict__ segtot)
{
    __shared__ unsigned sc[NBLK];
    int s = blockIdx.x;
    int t = threadIdx.x;
    unsigned v = blockhist[s * NBLK + t];
    sc[t] = v;
    __syncthreads();
    for (int off = 1; off < NBLK; off <<= 1) {
        unsigned add = (t >= off) ? sc[t - off] : 0u;
        __syncthreads();
        sc[t] += add;
        __syncthreads();
    }
    blockhist[s * NBLK + t] = sc[t] - v;      // exclusive over blocks
    if (t == NBLK - 1) segtot[s] = sc[t];
}

// ------------------------------------------- C: bounds from seg totals
__global__ __launch_bounds__(256) void gn_bounds(
    const unsigned* __restrict__ segtot, unsigned* __restrict__ boundsU,
    float* __restrict__ gcntf)
{
    __shared__ unsigned sc[SEG_CAP];
    int t = threadIdx.x;
    unsigned c = segtot[t];
    sc[t] = c;
    __syncthreads();
    for (int off = 1; off < SEG_CAP; off <<= 1) {
        unsigned add = (t >= off) ? sc[t - off] : 0u;
        __syncthreads();
        sc[t] += add;
        __syncthreads();
    }
    boundsU[t] = sc[t] - c;                   // exclusive; flat past S => bounds[S]=total
    gcntf[t]   = (float)c;
    if (t == SEG_CAP - 1) boundsU[SEG_CAP] = sc[t];
}

// ---------------------------------------------------------- D: scatter
__global__ __launch_bounds__(256) void gn_scatter_det(
    const int* __restrict__ seg, const unsigned* __restrict__ blockhist,
    const unsigned* __restrict__ boundsU, unsigned* __restrict__ rowidx, int N)
{
    __shared__ unsigned basep[SEG_CAP];
    __shared__ unsigned lcur [SEG_CAP];
    int b = blockIdx.x;
    for (int t = threadIdx.x; t < SEG_CAP; t += 256) {
        basep[t] = boundsU[t] + blockhist[t * NBLK + b];
        lcur[t]  = 0u;
    }
    __syncthreads();
    int chunk = (N + NBLK - 1) / NBLK;
    int start = b * chunk;
    int end   = min(N, start + chunk);
    for (int r = start + threadIdx.x; r < end; r += 256) {
        int s = seg[r];
        if ((unsigned)s < SEG_CAP) {
            unsigned lr = atomicAdd(&lcur[s], 1u);   // LDS, uncontended-ish
            rowidx[basep[s] + lr] = (unsigned)r;
        }
    }
}

// ------------------------------------------------------- E: reduce (sorted)
__global__ __launch_bounds__(256) void gn_reduce(
    const float4* __restrict__ x, const unsigned* __restrict__ rowidx,
    const unsigned* __restrict__ boundsU,
    float* __restrict__ gsum, float* __restrict__ gsq,
    const int* __restrict__ nInstPtr, int N)
{
    __shared__ int sb[SEG_CAP + 1];
    int S = *nInstPtr;
    if (S > SEG_CAP) S = SEG_CAP;
    for (int t = threadIdx.x; t <= S; t += blockDim.x) sb[t] = (int)boundsU[t];
    __syncthreads();

    const int h = threadIdx.x >> 5;     // half-wave id 0..7
    const int g = threadIdx.x & 31;     // group id
    int chunk = (N + gridDim.x - 1) / gridDim.x;
    int start = blockIdx.x * chunk;
    int end   = min(N, start + chunk);
    int p = start + h;
    if (p >= end) return;

    int lo = 0, hi = S - 1;             // largest k with sb[k] <= p
    while (lo < hi) {
        int mid = (lo + hi) >> 1;
        if (sb[mid + 1] <= p) lo = mid + 1; else hi = mid;
    }
    int k = lo;

    float asum = 0.f, asq = 0.f;
    for (; p < end; p += 8) {
        while (p >= sb[k + 1]) {
            if (asum != 0.f || asq != 0.f) {
                unsafeAtomicAdd(&gsum[k * GROUPS + g], asum);
                unsafeAtomicAdd(&gsq [k * GROUPS + g], asq);
                asum = 0.f; asq = 0.f;
            }
            ++k;
        }
        int r = (int)rowidx[p];
        float4 v = x[(long long)r * GROUPS + g];
        asum += (v.x + v.y) + (v.z + v.w);
        asq  += v.x*v.x + v.y*v.y + v.z*v.z + v.w*v.w;
    }
    if (asum != 0.f || asq != 0.f) {
        unsafeAtomicAdd(&gsum[k * GROUPS + g], asum);
        unsafeAtomicAdd(&gsq [k * GROUPS + g], asq);
    }
}

// ---------------------------------------------------------------- F: finalize
__global__ __launch_bounds__(256) void gn_finalize(
    const float* __restrict__ gsum, const float* __restrict__ gsq,
    const float* __restrict__ gcnt, float2* __restrict__ stats,
    const int* __restrict__ nInstPtr)
{
    int S = *nInstPtr;
    int i = blockIdx.x * blockDim.x + threadIdx.x;
    if (i < S * GROUPS) {
        int s = i >> 5;
        float cnt = gcnt[s];
        float denom = fmaxf(cnt * 4.0f, 1.0f);
        float mean = gsum[i] / denom;
        float var  = gsq[i] / denom - mean * mean;
        float inv  = rsqrtf(var + EPS);
        stats[i] = make_float2(mean, inv);
    }
}

// ----------------------------------------------------- G: pass2 (sorted order)
__global__ __launch_bounds__(256) void gn_pass2_sorted(
    const float4* __restrict__ x, const int* __restrict__ seg,
    const unsigned* __restrict__ rowidx, const float2* __restrict__ stats,
    const float4* __restrict__ gamma4, const float4* __restrict__ beta4,
    float4* __restrict__ out, int N)
{
    const int h = threadIdx.x >> 5;     // half-wave: one row per step
    const int g = threadIdx.x & 31;
    const float4 gm = gamma4[g];
    const float4 bt = beta4[g];
    int chunk = (N + gridDim.x - 1) / gridDim.x;
    int start = blockIdx.x * chunk;
    int end   = min(N, start + chunk);
    int p = start + h;

    for (; p + 8 < end; p += 16) {
        int r0 = (int)rowidx[p];
        int r1 = (int)rowidx[p + 8];
        int s0 = seg[r0];
        int s1 = seg[r1];
        float4 v0 = x[(long long)r0 * GROUPS + g];
        float4 v1 = x[(long long)r1 * GROUPS + g];
        float2 t0 = stats[s0 * GROUPS + g];
        float2 t1 = stats[s1 * GROUPS + g];
        float4 o0, o1;
        o0.x = (v0.x - t0.x) * t0.y * gm.x + bt.x;
        o0.y = (v0.y - t0.x) * t0.y * gm.y + bt.y;
        o0.z = (v0.z - t0.x) * t0.y * gm.z + bt.z;
        o0.w = (v0.w - t0.x) * t0.y * gm.w + bt.w;
        o1.x = (v1.x - t1.x) * t1.y * gm.x + bt.x;
        o1.y = (v1.y - t1.x) * t1.y * gm.y + bt.y;
        o1.z = (v1.z - t1.x) * t1.y * gm.z + bt.z;
        o1.w = (v1.w - t1.x) * t1.y * gm.w + bt.w;
        nt_store4(&out[(long long)r0 * GROUPS + g], o0);
        nt_store4(&out[(long long)r1 * GROUPS + g], o1);
    }
    for (; p < end; p += 8) {
        int r = (int)rowidx[p];
        int s = seg[r];
        float4 v = x[(long long)r * GROUPS + g];
        float2 t = stats[s * GROUPS + g];
        float4 o;
        o.x = (v.x - t.x) * t.y * gm.x + bt.x;
        o.y = (v.y - t.x) * t.y * gm.y + bt.y;
        o.z = (v.z - t.x) * t.y * gm.z + bt.z;
        o.w = (v.w - t.x) * t.y * gm.w + bt.w;
        nt_store4(&out[(long long)r * GROUPS + g], o);
    }
}

// -------------------------------------------------------------- legacy pass1
__device__ __forceinline__ void lds_fadd(float* p, float v) {
    asm volatile("ds_add_f32 %0, %1"
                 :: "v"((unsigned)(unsigned long long)p), "v"(v));
}

__global__ __launch_bounds__(256) void gn_pass1(
    const float4* __restrict__ x, const int* __restrict__ seg,
    float* __restrict__ gsum, float* __restrict__ gsq, float* __restrict__ gcnt,
    const int* __restrict__ nInstPtr, int N)
{
    __shared__ float lsum[LDS_SEG_CAP * GROUPS];
    __shared__ float lsq [LDS_SEG_CAP * GROUPS];
    __shared__ float lcnt[LDS_SEG_CAP];
    for (int t = threadIdx.x; t < LDS_SEG_CAP * GROUPS; t += blockDim.x) {
        lsum[t] = 0.f; lsq[t] = 0.f;
    }
    for (int t = threadIdx.x; t < LDS_SEG_CAP; t += blockDim.x) lcnt[t] = 0.f;
    __syncthreads();

    const int g = threadIdx.x & 31;
    const long long total  = (long long)N * GROUPS;
    const long long stride = (long long)gridDim.x * blockDim.x;
    long long i = (long long)blockIdx.x * blockDim.x + threadIdx.x;
    for (; i < total; i += stride) {
        int row = (int)(i >> 5);
        float4 v = x[i];
        int s = seg[row];
        float a = (v.x + v.y) + (v.z + v.w);
        float q = v.x*v.x + v.y*v.y + v.z*v.z + v.w*v.w;
        if (s < LDS_SEG_CAP) {
            lds_fadd(&lsum[s * GROUPS + g], a);
            lds_fadd(&lsq [s * GROUPS + g], q);
            if (g == 0) lds_fadd(&lcnt[s], 1.0f);
        } else {
            unsafeAtomicAdd(&gsum[s * GROUPS + g], a);
            unsafeAtomicAdd(&gsq [s * GROUPS + g], q);
            if (g == 0) unsafeAtomicAdd(&gcnt[s], 1.0f);
        }
    }
    asm volatile("s_waitcnt lgkmcnt(0)" ::: "memory");
    __syncthreads();

    int S = *nInstPtr;
    int lim = min(S, LDS_SEG_CAP);
    int nb = lim * GROUPS;
    int rot = (int)((blockIdx.x * 64u) % (unsigned)nb);
    for (int t = threadIdx.x; t < nb; t += blockDim.x) {
        int j = t + rot; if (j >= nb) j -= nb;
        float a = lsum[j], b = lsq[j];
        if (a != 0.f || b != 0.f) {
            unsafeAtomicAdd(&gsum[j], a);
            unsafeAtomicAdd(&gsq [j], b);
        }
    }
    for (int t = threadIdx.x; t < lim; t += blockDim.x) {
        float c = lcnt[t];
        if (c != 0.f) unsafeAtomicAdd(&gcnt[t], c);
    }
}

// -------------------------------------------------------------- legacy pass2
__global__ __launch_bounds__(256) void gn_pass2(
    const float4* __restrict__ x, const int* __restrict__ seg,
    const float2* __restrict__ stats,
    const float4* __restrict__ gamma4, const float4* __restrict__ beta4,
    float4* __restrict__ out, int N)
{
    const int g = threadIdx.x & 31;
    const float4 gm = gamma4[g];
    const float4 bt = beta4[g];
    const long long total  = (long long)N * GROUPS;
    const long long stride = (long long)gridDim.x * blockDim.x;
    for (long long i = (long long)blockIdx.x * blockDim.x + threadIdx.x;
         i < total; i += stride) {
        int row = (int)(i >> 5);
        float4 v = x[i];
        int s = seg[row];
        float2 mi = stats[s * GROUPS + g];
        float4 o;
        o.x = (v.x - mi.x) * mi.y * gm.x + bt.x;
        o.y = (v.y - mi.x) * mi.y * gm.y + bt.y;
        o.z = (v.z - mi.x) * mi.y * gm.z + bt.z;
        o.w = (v.w - mi.x) * mi.y * gm.w + bt.w;
        nt_store4(&out[i], o);
    }
}

extern "C" void kernel_launch(void* const* d_in, const int* in_sizes, int n_in,
                              void* d_out, int out_size, void* d_ws, size_t ws_size,
                              hipStream_t stream) {
    const float* feat  = (const float*)d_in[0];
    const int*   seg   = (const int*)d_in[1];
    const float* gamma = (const float*)d_in[2];
    const float* beta  = (const float*)d_in[3];
    const int*   nInst = (const int*)d_in[4];
    const int N = in_sizes[0] / C_CHANNELS;

    // ws layout (float-offset units):
    //   gsum      @0        [8192]f
    //   gsq       @8192     [8192]f
    //   segtot    @16384    [256]u32
    //   gcntf     @16640    [256]f
    //   (unused)  @16896    [256]
    //   boundsU   @17152    [260]u32
    //   stats     @17412    [8192]float2
    //   rowidx    @33796    [N]u32
    //   blockhist @33796+N  [SEG_CAP*NBLK]u32
    float*    base    = (float*)d_ws;
    float*    gsum    = base;
    float*    gsq     = base + 8192;
    unsigned* segtot  = (unsigned*)(base + 16384);
    float*    gcntf   = base + 16640;
    unsigned* boundsU = (unsigned*)(base + 17152);
    float2*   stats   = (float2*)(base + 17412);
    unsigned* rowidx  = (unsigned*)(base + 33796);
    unsigned* blockhist = rowidx + N;

    size_t need = ((size_t)33796 + (size_t)N + (size_t)SEG_CAP * NBLK) * 4;
    bool use_sorted = (ws_size >= need);

    if (use_sorted) {
        (void)hipMemsetAsync(d_ws, 0, (size_t)16384 * 4, stream);  // gsum|gsq

        gn_histlocal<<<NBLK, 256, 0, stream>>>(seg, blockhist, N);
        gn_scanseg<<<SEG_CAP, 256, 0, stream>>>(blockhist, segtot);
        gn_bounds<<<1, 256, 0, stream>>>(segtot, boundsU, gcntf);
        gn_scatter_det<<<NBLK, 256, 0, stream>>>(seg, blockhist, boundsU, rowidx, N);
        gn_reduce<<<2048, 256, 0, stream>>>(
            (const float4*)feat, rowidx, boundsU, gsum, gsq, nInst, N);
        gn_finalize<<<(SEG_CAP * GROUPS + 255) / 256, 256, 0, stream>>>(
            gsum, gsq, gcntf, stats, nInst);
        gn_pass2_sorted<<<2048, 256, 0, stream>>>(
            (const float4*)feat, seg, rowidx, stats,
            (const float4*)gamma, (const float4*)beta,
            (float4*)d_out, N);
    } else {
        (void)hipMemsetAsync(d_ws, 0, (size_t)(16384 + 512) * 4, stream);
        gn_pass1<<<1536, 256, 0, stream>>>(
            (const float4*)feat, seg, gsum, gsq, gcntf, nInst, N);
        gn_finalize<<<(SEG_CAP * GROUPS + 255) / 256, 256, 0, stream>>>(
            gsum, gsq, gcntf, stats, nInst);
        gn_pass2<<<2048, 256, 0, stream>>>(
            (const float4*)feat, seg, stats,
            (const float4*)gamma, (const float4*)beta,
            (float4*)d_out, N);
    }
}

// Round 5
// 993.146 us; speedup vs baseline: 1.9816x; 1.0209x over previous
//
#include <hip/hip_runtime.h>

// Segmented GroupNorm: N rows x C=128 channels, G=32 groups, Cg=4.
// group g == float4 element index (i & 31); channels 4g..4g+3.
//
// Pipeline (deterministic counting sort, zero contended global atomics):
//   A gn_histlocal : per-block histogram of seg -> blockhist[s][b]
//   B gn_scanseg   : per-seg exclusive scan over blocks
//   C gn_bounds    : scan of seg totals -> bounds, counts
//   D gn_scatter_det: block base = bounds[s]+blockhist[s][b]; LDS rank atomics
//   E gn_reduce    : register-accumulating segmented reduce over sorted rows.
//                    Segment of position p is seg[rowidx[p]] directly -- no
//                    boundary table walk -> 4x independent gathers in flight.
//   F gn_finalize  : mean/inv -> float2 stats table
//   G gn_pass2_sorted: gather-normalize-scatter in sorted order, 4x batched.
// Legacy DS-atomic pass1 + linear pass2 kept as fallback if ws too small.

#define C_CHANNELS 128
#define GROUPS 32
#define SEG_CAP 256
#define NBLK 256           // blocks for histlocal/scanseg/scatter (fixed)
#define LDS_SEG_CAP 104    // legacy path LDS bin capacity
#define EPS 1e-5f

typedef float f32x4 __attribute__((ext_vector_type(4)));

__device__ __forceinline__ void nt_store4(float4* p, const float4& v) {
    f32x4 t; t.x = v.x; t.y = v.y; t.z = v.z; t.w = v.w;
    __builtin_nontemporal_store(t, (f32x4*)p);
}

// ---------------------------------------------------------- A: local histogram
__global__ __launch_bounds__(256) void gn_histlocal(
    const int* __restrict__ seg, unsigned* __restrict__ blockhist, int N)
{
    __shared__ unsigned h[SEG_CAP];
    for (int t = threadIdx.x; t < SEG_CAP; t += 256) h[t] = 0u;
    __syncthreads();
    int chunk = (N + NBLK - 1) / NBLK;
    int start = blockIdx.x * chunk;
    int end   = min(N, start + chunk);
    for (int r = start + threadIdx.x; r < end; r += 256) {
        int s = seg[r];
        if ((unsigned)s < SEG_CAP) atomicAdd(&h[s], 1u);
    }
    __syncthreads();
    for (int t = threadIdx.x; t < SEG_CAP; t += 256)
        blockhist[t * NBLK + blockIdx.x] = h[t];
}

// ------------------------------------------- B: per-seg scan over blocks
__global__ __launch_bounds__(256) void gn_scanseg(
    unsigned* __restrict__ blockhist, unsigned* __restrict__ segtot)
{
    __shared__ unsigned sc[NBLK];
    int s = blockIdx.x;
    int t = threadIdx.x;
    unsigned v = blockhist[s * NBLK + t];
    sc[t] = v;
    __syncthreads();
    for (int off = 1; off < NBLK; off <<= 1) {
        unsigned add = (t >= off) ? sc[t - off] : 0u;
        __syncthreads();
        sc[t] += add;
        __syncthreads();
    }
    blockhist[s * NBLK + t] = sc[t] - v;      // exclusive over blocks
    if (t == NBLK - 1) segtot[s] = sc[t];
}

// ------------------------------------------- C: bounds from seg totals
__global__ __launch_bounds__(256) void gn_bounds(
    const unsigned* __restrict__ segtot, unsigned* __restrict__ boundsU,
    float* __restrict__ gcntf)
{
    __shared__ unsigned sc[SEG_CAP];
    int t = threadIdx.x;
    unsigned c = segtot[t];
    sc[t] = c;
    __syncthreads();
    for (int off = 1; off < SEG_CAP; off <<= 1) {
        unsigned add = (t >= off) ? sc[t - off] : 0u;
        __syncthreads();
        sc[t] += add;
        __syncthreads();
    }
    boundsU[t] = sc[t] - c;
    gcntf[t]   = (float)c;
    if (t == SEG_CAP - 1) boundsU[SEG_CAP] = sc[t];
}

// ---------------------------------------------------------- D: scatter
__global__ __launch_bounds__(256) void gn_scatter_det(
    const int* __restrict__ seg, const unsigned* __restrict__ blockhist,
    const unsigned* __restrict__ boundsU, unsigned* __restrict__ rowidx, int N)
{
    __shared__ unsigned basep[SEG_CAP];
    __shared__ unsigned lcur [SEG_CAP];
    int b = blockIdx.x;
    for (int t = threadIdx.x; t < SEG_CAP; t += 256) {
        basep[t] = boundsU[t] + blockhist[t * NBLK + b];
        lcur[t]  = 0u;
    }
    __syncthreads();
    int chunk = (N + NBLK - 1) / NBLK;
    int start = b * chunk;
    int end   = min(N, start + chunk);
    for (int r = start + threadIdx.x; r < end; r += 256) {
        int s = seg[r];
        if ((unsigned)s < SEG_CAP) {
            unsigned lr = atomicAdd(&lcur[s], 1u);   // LDS rank
            rowidx[basep[s] + lr] = (unsigned)r;
        }
    }
}

// ------------------------------------------------------- E: reduce (sorted)
// Half-wave h visits positions start+h, +8, ... Lane g accumulates (sum,sq)
// for its group in registers; flush via global atomic only when the run's
// segment changes. Segment comes from seg[rowidx[p]] directly, so the 4
// batched gathers are fully independent -> 4 HBM loads in flight/half-wave.
__global__ __launch_bounds__(256) void gn_reduce(
    const float4* __restrict__ x, const unsigned* __restrict__ rowidx,
    const int* __restrict__ seg,
    float* __restrict__ gsum, float* __restrict__ gsq, int N)
{
    const int h = threadIdx.x >> 5;
    const int g = threadIdx.x & 31;
    int chunk = (N + gridDim.x - 1) / gridDim.x;
    int start = blockIdx.x * chunk;
    int end   = min(N, start + chunk);
    int p = start + h;

    float asum = 0.f, asq = 0.f;
    int cur = -1;

#define GN_ACC(S_, V_) do {                                         \
        if (S_ != cur) {                                            \
            if (cur >= 0 && (asum != 0.f || asq != 0.f)) {          \
                unsafeAtomicAdd(&gsum[cur * GROUPS + g], asum);     \
                unsafeAtomicAdd(&gsq [cur * GROUPS + g], asq);      \
            }                                                       \
            cur = S_; asum = 0.f; asq = 0.f;                        \
        }                                                           \
        asum += (V_.x + V_.y) + (V_.z + V_.w);                      \
        asq  += V_.x*V_.x + V_.y*V_.y + V_.z*V_.z + V_.w*V_.w;      \
    } while (0)

    for (; p + 24 < end; p += 32) {
        int r0 = (int)rowidx[p];
        int r1 = (int)rowidx[p + 8];
        int r2 = (int)rowidx[p + 16];
        int r3 = (int)rowidx[p + 24];
        int s0 = seg[r0];
        int s1 = seg[r1];
        int s2 = seg[r2];
        int s3 = seg[r3];
        float4 v0 = x[(long long)r0 * GROUPS + g];
        float4 v1 = x[(long long)r1 * GROUPS + g];
        float4 v2 = x[(long long)r2 * GROUPS + g];
        float4 v3 = x[(long long)r3 * GROUPS + g];
        GN_ACC(s0, v0);
        GN_ACC(s1, v1);
        GN_ACC(s2, v2);
        GN_ACC(s3, v3);
    }
    for (; p < end; p += 8) {
        int r = (int)rowidx[p];
        int s = seg[r];
        float4 v = x[(long long)r * GROUPS + g];
        GN_ACC(s, v);
    }
    if (cur >= 0 && (asum != 0.f || asq != 0.f)) {
        unsafeAtomicAdd(&gsum[cur * GROUPS + g], asum);
        unsafeAtomicAdd(&gsq [cur * GROUPS + g], asq);
    }
#undef GN_ACC
}

// ---------------------------------------------------------------- F: finalize
__global__ __launch_bounds__(256) void gn_finalize(
    const float* __restrict__ gsum, const float* __restrict__ gsq,
    const float* __restrict__ gcnt, float2* __restrict__ stats,
    const int* __restrict__ nInstPtr)
{
    int S = *nInstPtr;
    int i = blockIdx.x * blockDim.x + threadIdx.x;
    if (i < S * GROUPS) {
        int s = i >> 5;
        float cnt = gcnt[s];
        float denom = fmaxf(cnt * 4.0f, 1.0f);
        float mean = gsum[i] / denom;
        float var  = gsq[i] / denom - mean * mean;
        float inv  = rsqrtf(var + EPS);
        stats[i] = make_float2(mean, inv);
    }
}

// ----------------------------------------------------- G: pass2 (sorted order)
__global__ __launch_bounds__(256) void gn_pass2_sorted(
    const float4* __restrict__ x, const int* __restrict__ seg,
    const unsigned* __restrict__ rowidx, const float2* __restrict__ stats,
    const float4* __restrict__ gamma4, const float4* __restrict__ beta4,
    float4* __restrict__ out, int N)
{
    const int h = threadIdx.x >> 5;
    const int g = threadIdx.x & 31;
    const float4 gm = gamma4[g];
    const float4 bt = beta4[g];
    int chunk = (N + gridDim.x - 1) / gridDim.x;
    int start = blockIdx.x * chunk;
    int end   = min(N, start + chunk);
    int p = start + h;

#define GN_NRM(V_, T_, O_)                                   \
        O_.x = (V_.x - T_.x) * T_.y * gm.x + bt.x;           \
        O_.y = (V_.y - T_.x) * T_.y * gm.y + bt.y;           \
        O_.z = (V_.z - T_.x) * T_.y * gm.z + bt.z;           \
        O_.w = (V_.w - T_.x) * T_.y * gm.w + bt.w;

    for (; p + 24 < end; p += 32) {
        int r0 = (int)rowidx[p];
        int r1 = (int)rowidx[p + 8];
        int r2 = (int)rowidx[p + 16];
        int r3 = (int)rowidx[p + 24];
        int s0 = seg[r0];
        int s1 = seg[r1];
        int s2 = seg[r2];
        int s3 = seg[r3];
        float4 v0 = x[(long long)r0 * GROUPS + g];
        float4 v1 = x[(long long)r1 * GROUPS + g];
        float4 v2 = x[(long long)r2 * GROUPS + g];
        float4 v3 = x[(long long)r3 * GROUPS + g];
        float2 t0 = stats[s0 * GROUPS + g];
        float2 t1 = stats[s1 * GROUPS + g];
        float2 t2 = stats[s2 * GROUPS + g];
        float2 t3 = stats[s3 * GROUPS + g];
        float4 o0, o1, o2, o3;
        GN_NRM(v0, t0, o0);
        GN_NRM(v1, t1, o1);
        GN_NRM(v2, t2, o2);
        GN_NRM(v3, t3, o3);
        nt_store4(&out[(long long)r0 * GROUPS + g], o0);
        nt_store4(&out[(long long)r1 * GROUPS + g], o1);
        nt_store4(&out[(long long)r2 * GROUPS + g], o2);
        nt_store4(&out[(long long)r3 * GROUPS + g], o3);
    }
    for (; p < end; p += 8) {
        int r = (int)rowidx[p];
        int s = seg[r];
        float4 v = x[(long long)r * GROUPS + g];
        float2 t = stats[s * GROUPS + g];
        float4 o;
        GN_NRM(v, t, o);
        nt_store4(&out[(long long)r * GROUPS + g], o);
    }
#undef GN_NRM
}

// -------------------------------------------------------------- legacy pass1
__device__ __forceinline__ void lds_fadd(float* p, float v) {
    asm volatile("ds_add_f32 %0, %1"
                 :: "v"((unsigned)(unsigned long long)p), "v"(v));
}

__global__ __launch_bounds__(256) void gn_pass1(
    const float4* __restrict__ x, const int* __restrict__ seg,
    float* __restrict__ gsum, float* __restrict__ gsq, float* __restrict__ gcnt,
    const int* __restrict__ nInstPtr, int N)
{
    __shared__ float lsum[LDS_SEG_CAP * GROUPS];
    __shared__ float lsq [LDS_SEG_CAP * GROUPS];
    __shared__ float lcnt[LDS_SEG_CAP];
    for (int t = threadIdx.x; t < LDS_SEG_CAP * GROUPS; t += blockDim.x) {
        lsum[t] = 0.f; lsq[t] = 0.f;
    }
    for (int t = threadIdx.x; t < LDS_SEG_CAP; t += blockDim.x) lcnt[t] = 0.f;
    __syncthreads();

    const int g = threadIdx.x & 31;
    const long long total  = (long long)N * GROUPS;
    const long long stride = (long long)gridDim.x * blockDim.x;
    long long i = (long long)blockIdx.x * blockDim.x + threadIdx.x;
    for (; i < total; i += stride) {
        int row = (int)(i >> 5);
        float4 v = x[i];
        int s = seg[row];
        float a = (v.x + v.y) + (v.z + v.w);
        float q = v.x*v.x + v.y*v.y + v.z*v.z + v.w*v.w;
        if (s < LDS_SEG_CAP) {
            lds_fadd(&lsum[s * GROUPS + g], a);
            lds_fadd(&lsq [s * GROUPS + g], q);
            if (g == 0) lds_fadd(&lcnt[s], 1.0f);
        } else {
            unsafeAtomicAdd(&gsum[s * GROUPS + g], a);
            unsafeAtomicAdd(&gsq [s * GROUPS + g], q);
            if (g == 0) unsafeAtomicAdd(&gcnt[s], 1.0f);
        }
    }
    asm volatile("s_waitcnt lgkmcnt(0)" ::: "memory");
    __syncthreads();

    int S = *nInstPtr;
    int lim = min(S, LDS_SEG_CAP);
    int nb = lim * GROUPS;
    int rot = (int)((blockIdx.x * 64u) % (unsigned)nb);
    for (int t = threadIdx.x; t < nb; t += blockDim.x) {
        int j = t + rot; if (j >= nb) j -= nb;
        float a = lsum[j], b = lsq[j];
        if (a != 0.f || b != 0.f) {
            unsafeAtomicAdd(&gsum[j], a);
            unsafeAtomicAdd(&gsq [j], b);
        }
    }
    for (int t = threadIdx.x; t < lim; t += blockDim.x) {
        float c = lcnt[t];
        if (c != 0.f) unsafeAtomicAdd(&gcnt[t], c);
    }
}

// -------------------------------------------------------------- legacy pass2
__global__ __launch_bounds__(256) void gn_pass2(
    const float4* __restrict__ x, const int* __restrict__ seg,
    const float2* __restrict__ stats,
    const float4* __restrict__ gamma4, const float4* __restrict__ beta4,
    float4* __restrict__ out, int N)
{
    const int g = threadIdx.x & 31;
    const float4 gm = gamma4[g];
    const float4 bt = beta4[g];
    const long long total  = (long long)N * GROUPS;
    const long long stride = (long long)gridDim.x * blockDim.x;
    for (long long i = (long long)blockIdx.x * blockDim.x + threadIdx.x;
         i < total; i += stride) {
        int row = (int)(i >> 5);
        float4 v = x[i];
        int s = seg[row];
        float2 mi = stats[s * GROUPS + g];
        float4 o;
        o.x = (v.x - mi.x) * mi.y * gm.x + bt.x;
        o.y = (v.y - mi.x) * mi.y * gm.y + bt.y;
        o.z = (v.z - mi.x) * mi.y * gm.z + bt.z;
        o.w = (v.w - mi.x) * mi.y * gm.w + bt.w;
        nt_store4(&out[i], o);
    }
}

extern "C" void kernel_launch(void* const* d_in, const int* in_sizes, int n_in,
                              void* d_out, int out_size, void* d_ws, size_t ws_size,
                              hipStream_t stream) {
    const float* feat  = (const float*)d_in[0];
    const int*   seg   = (const int*)d_in[1];
    const float* gamma = (const float*)d_in[2];
    const float* beta  = (const float*)d_in[3];
    const int*   nInst = (const int*)d_in[4];
    const int N = in_sizes[0] / C_CHANNELS;

    // ws layout (float-offset units):
    //   gsum      @0        [8192]f
    //   gsq       @8192     [8192]f
    //   segtot    @16384    [256]u32
    //   gcntf     @16640    [256]f
    //   (unused)  @16896    [256]
    //   boundsU   @17152    [260]u32
    //   stats     @17412    [8192]float2
    //   rowidx    @33796    [N]u32
    //   blockhist @33796+N  [SEG_CAP*NBLK]u32
    float*    base    = (float*)d_ws;
    float*    gsum    = base;
    float*    gsq     = base + 8192;
    unsigned* segtot  = (unsigned*)(base + 16384);
    float*    gcntf   = base + 16640;
    unsigned* boundsU = (unsigned*)(base + 17152);
    float2*   stats   = (float2*)(base + 17412);
    unsigned* rowidx  = (unsigned*)(base + 33796);
    unsigned* blockhist = rowidx + N;

    size_t need = ((size_t)33796 + (size_t)N + (size_t)SEG_CAP * NBLK) * 4;
    bool use_sorted = (ws_size >= need);

    if (use_sorted) {
        (void)hipMemsetAsync(d_ws, 0, (size_t)16384 * 4, stream);  // gsum|gsq

        gn_histlocal<<<NBLK, 256, 0, stream>>>(seg, blockhist, N);
        gn_scanseg<<<SEG_CAP, 256, 0, stream>>>(blockhist, segtot);
        gn_bounds<<<1, 256, 0, stream>>>(segtot, boundsU, gcntf);
        gn_scatter_det<<<NBLK, 256, 0, stream>>>(seg, blockhist, boundsU, rowidx, N);
        gn_reduce<<<2048, 256, 0, stream>>>(
            (const float4*)feat, rowidx, seg, gsum, gsq, N);
        gn_finalize<<<(SEG_CAP * GROUPS + 255) / 256, 256, 0, stream>>>(
            gsum, gsq, gcntf, stats, nInst);
        gn_pass2_sorted<<<2048, 256, 0, stream>>>(
            (const float4*)feat, seg, rowidx, stats,
            (const float4*)gamma, (const float4*)beta,
            (float4*)d_out, N);
    } else {
        (void)hipMemsetAsync(d_ws, 0, (size_t)(16384 + 512) * 4, stream);
        gn_pass1<<<1536, 256, 0, stream>>>(
            (const float4*)feat, seg, gsum, gsq, gcntf, nInst, N);
        gn_finalize<<<(SEG_CAP * GROUPS + 255) / 256, 256, 0, stream>>>(
            gsum, gsq, gcntf, stats, nInst);
        gn_pass2<<<2048, 256, 0, stream>>>(
            (const float4*)feat, seg, stats,
            (const float4*)gamma, (const float4*)beta,
            (float4*)d_out, N);
    }
}